// Round 3
// baseline (108.117 us; speedup 1.0000x reference)
//
#include <hip/hip_runtime.h>
#include <hip/hip_bf16.h>
#include <math.h>

#define BB 2
#define NN 16384
#define KK 16
#define CC 128
#define COUT 128
#define NODES (BB * NN)
#define SP 136   // bf16 staging row pitch (elements; 272 B -> 68 dwords, bank-uniform)
#define SQP 136  // fp8 staging row pitch (bytes)
#define ZP 136   // z-tile row pitch (elements)
#define XBLK 2048

typedef __attribute__((ext_vector_type(8))) short bf16x8;
typedef __attribute__((ext_vector_type(4))) float f32x4;
typedef __attribute__((ext_vector_type(2))) float f32x2;  // matches fp8 builtin returns

__device__ __forceinline__ bf16x8 cvt8(f32x4 a, f32x4 b) {
    union { bf16x8 v; __hip_bfloat162 h[4]; } u;
    u.h[0] = __float22bfloat162_rn(make_float2(a[0], a[1]));
    u.h[1] = __float22bfloat162_rn(make_float2(a[2], a[3]));
    u.h[2] = __float22bfloat162_rn(make_float2(b[0], b[1]));
    u.h[3] = __float22bfloat162_rn(make_float2(b[2], b[3]));
    return u.v;
}

// DPP row_ror adds within each 16-lane row (VALU pipe).
template <int CTRL>
__device__ __forceinline__ float rot_add(float v) {
    int r = __builtin_amdgcn_update_dpp(0, __float_as_int(v), CTRL, 0xF, 0xF, true);
    return v + __int_as_float(r);
}
__device__ __forceinline__ float row16_sum(float v) {
    v = rot_add<0x128>(v); v = rot_add<0x124>(v);
    v = rot_add<0x122>(v); v = rot_add<0x121>(v);
    return v;
}
__device__ __forceinline__ float row16_sum4(float v) {
    v = rot_add<0x128>(v); v = rot_add<0x124>(v);
    return v;
}

// ---------------------------------------------------------------------------
// Kernel P: x (fp32) -> xh (bf16) + xq (fp8 e4m3), streaming. 8 elems/thread.
// Tail blocks cast W fp32 -> wh bf16 (same cvt8 rounding as before).
// ---------------------------------------------------------------------------
__global__ __launch_bounds__(256) void cast_x(
    const float* __restrict__ x,
    __hip_bfloat16* __restrict__ xh,
    unsigned char* __restrict__ xq,
    const float* __restrict__ W,
    __hip_bfloat16* __restrict__ wh)
{
    const int bid = blockIdx.x;
    if (bid >= XBLK) {
        const int i = (bid - XBLK) * 256 + threadIdx.x;
        const f32x4* p = (const f32x4*)(W + (size_t)i * 8);
        f32x4 a = p[0];
        f32x4 b = p[1];
        *(bf16x8*)(wh + (size_t)i * 8) = cvt8(a, b);
        return;
    }
    const int i = bid * 256 + threadIdx.x;
    const f32x4* p = (const f32x4*)(x + (size_t)i * 8);
    f32x4 a = __builtin_nontemporal_load(p);
    f32x4 b = __builtin_nontemporal_load(p + 1);
    *(bf16x8*)(xh + (size_t)i * 8) = cvt8(a, b);
    int lo = __builtin_amdgcn_cvt_pk_fp8_f32(a[0], a[1], 0, false);
    lo     = __builtin_amdgcn_cvt_pk_fp8_f32(a[2], a[3], lo, true);
    int hi = __builtin_amdgcn_cvt_pk_fp8_f32(b[0], b[1], 0, false);
    hi     = __builtin_amdgcn_cvt_pk_fp8_f32(b[2], b[3], hi, true);
    int2 v; v.x = lo; v.y = hi;
    *(int2*)(xq + (size_t)i * 8) = v;
}

// Softmax column-sum: scores (C-layout) -> w for this lane's Xj row m.
__device__ __forceinline__ float col_weight(f32x4 acc) {
    const float scale = 0.08838834764831843f;  // 1/sqrt(128)
    float w = 0.f;
    #pragma unroll
    for (int i = 0; i < 4; ++i) {
        float e = __expf(acc[i] * scale);
        float s = row16_sum(e);
        w += e * __builtin_amdgcn_rcpf(s);
    }
    w += __shfl_xor(w, 16, 64);
    w += __shfl_xor(w, 32, 64);
    return w;
}

// h-reduction: lane's Xj row (bf16 frags) scaled by wj, DPP 16->4 rows +
// per-wave LDS bounce 4->1. Returns lane's channels (2L, 2L+1).
__device__ __forceinline__ float2 reduce_h(const bf16x8* bfr, float wj,
                                           float* hb, int m, int q, int lane) {
    #pragma unroll
    for (int s = 0; s < 4; ++s) {
        union { bf16x8 v; unsigned short u[8]; } ub;
        ub.v = bfr[s];
        float f[8];
        #pragma unroll
        for (int e = 0; e < 8; ++e) {
            f[e] = __uint_as_float((unsigned)ub.u[e] << 16) * wj;
            f[e] = row16_sum4(f[e]);
        }
        if (m < 4) {
            f32x4 lo = {f[0], f[1], f[2], f[3]};
            f32x4 hi = {f[4], f[5], f[6], f[7]};
            *(f32x4*)&hb[m * 132 + 32 * s + 8 * q]     = lo;
            *(f32x4*)&hb[m * 132 + 32 * s + 8 * q + 4] = hi;
        }
    }
    float hx = 0.f, hy = 0.f;
    #pragma unroll
    for (int r = 0; r < 4; ++r) {
        float2 v = *(const float2*)&hb[r * 132 + 2 * lane];
        hx += v.x; hy += v.y;
    }
    return make_float2(hx, hy);
}

struct Rows { int2 q[4]; bf16x8 j[4]; };

// Staged-gather shape (R0-proven): 4 inst x (4 rows x 128B) fp8,
// 4 inst x (4 rows x 256B) bf16 — few LONG segments per instruction.
// Edge indices arrive pre-hoisted in m-layout registers; redistribute to the
// (g,r) staging lane via register-only __shfl — no global load on the
// prefetch critical path.
__device__ __forceinline__ void gather_rows(
    int ejv, int eiv, int r, int c,
    const __hip_bfloat16* __restrict__ xbh,
    const unsigned char* __restrict__ xbq,
    Rows& g)
{
    #pragma unroll
    for (int gg = 0; gg < 4; ++gg) {
        int ri = __shfl(eiv, gg * 4 + r, 16);
        g.q[gg] = *(const int2*)(xbq + (size_t)ri * CC + c * 8);
    }
    #pragma unroll
    for (int gg = 0; gg < 4; ++gg) {
        int rj = __shfl(ejv, gg * 4 + r, 16);
        g.j[gg] = *(const bf16x8*)(xbh + (size_t)rj * CC + c * 8);
    }
}

// ---------------------------------------------------------------------------
// Fused kernel: block = 16 nodes (4 waves x 4 nodes serial), z tile in LDS,
// then the 16x128 @ 128x128 linear. This round:
//  - edge-index + residual loads hoisted to wave start (prefetch chain is
//    row-gather latency only, fits under the compute window)
//  - hbuf aliases stgq (per-wave 2176 B each, exact fit; in-order per-wave
//    DS: stgq of node `it` fully consumed before reduce_h writes, and
//    it+1 staging writes follow reduce_h reads in program order)
//  - LDS 39.2 -> 30.5 KB, __launch_bounds__(256,5): 5 blocks/CU if the
//    allocator fits 102 VGPR (fp8-upconvert fused into the MFMA loop to
//    drop the afr[4] array from peak pressure).
// ---------------------------------------------------------------------------
__global__ __launch_bounds__(256, 5) void attn_fused(
    const __hip_bfloat16* __restrict__ xh,
    const unsigned char* __restrict__ xq,
    const int* __restrict__ edge,
    const __hip_bfloat16* __restrict__ wh,
    const float* __restrict__ bias,
    float* __restrict__ out)
{
    __shared__ __hip_bfloat16 stgj[4][16 * SP];             // 17408 B
    __shared__ alignas(16) unsigned char stgq[4][16 * SQP]; // 8704 B (doubles as hbuf)
    __shared__ __hip_bfloat16 zt[16][ZP];                   // 4352 B

    const int t = threadIdx.x;
    const int wv = t >> 6;
    const int lane = t & 63;
    const int m = lane & 15;   // fragment row
    const int q = lane >> 4;   // fragment k-quad
    const int r = lane >> 4;   // staging: row-in-group 0..3
    const int c = lane & 15;   // staging: chunk within row
    const int base = blockIdx.x * 16;
    const int node0 = base + wv * 4;
    const int b = node0 >> 14;          // block of 16 nodes never straddles NN

    const __hip_bfloat16* xbh = xh + (size_t)b * (size_t)(NN * CC);
    const unsigned char*  xbq = xq + (size_t)b * (size_t)(NN * CC);
    __hip_bfloat16* sj = &stgj[wv][0];
    unsigned char*  sq = &stgq[wv][0];
    float*          hb = (float*)sq;    // alias

    // ---- hoisted edge indices (m-layout) + residual rows for all 4 nodes ----
    int ejv[4], eiv[4];
    __hip_bfloat162 rxv[4];
    #pragma unroll
    for (int n = 0; n < 4; ++n) {
        const int* ej = edge + (size_t)(node0 + n) * KK;
        ejv[n] = __builtin_nontemporal_load(ej + m);
        eiv[n] = __builtin_nontemporal_load(ej + (size_t)NODES * KK + m);
        const int nloc = (node0 + n) & (NN - 1);
        rxv[n] = *(const __hip_bfloat162*)(xbh + (size_t)nloc * CC + 2 * lane);
    }

    Rows cur, nxt;
    gather_rows(ejv[0], eiv[0], r, c, xbh, xbq, cur);

    #pragma unroll
    for (int it = 0; it < 4; ++it) {
        // ---- stage current node to LDS (wave-private; in-order DS) ----
        #pragma unroll
        for (int g = 0; g < 4; ++g)
            *(int2*)(sq + (g * 4 + r) * SQP + c * 8) = cur.q[g];
        #pragma unroll
        for (int g = 0; g < 4; ++g)
            *(bf16x8*)(sj + (g * 4 + r) * SP + c * 8) = cur.j[g];

        // ---- issue next node's row gathers (latency hides under compute) ----
        if (it < 3)
            gather_rows(ejv[it + 1], eiv[it + 1], r, c, xbh, xbq, nxt);

        // ---- fragments + scores: upconvert Xi fp8->bf16 fused into MFMA loop
        bf16x8 bfr[4];
        f32x4 acc = {0.f, 0.f, 0.f, 0.f};
        #pragma unroll
        for (int s = 0; s < 4; ++s) {
            int2 wb = *(const int2*)(sq + m * SQP + s * 32 + q * 8);
            bfr[s] = *(const bf16x8*)(sj + m * SP + s * 32 + q * 8);
            f32x2 f0 = __builtin_amdgcn_cvt_pk_f32_fp8(wb.x, false);
            f32x2 f1 = __builtin_amdgcn_cvt_pk_f32_fp8(wb.x, true);
            f32x2 f2 = __builtin_amdgcn_cvt_pk_f32_fp8(wb.y, false);
            f32x2 f3 = __builtin_amdgcn_cvt_pk_f32_fp8(wb.y, true);
            union { bf16x8 v; __hip_bfloat162 h[4]; } u;
            u.h[0] = __float22bfloat162_rn(make_float2(f0[0], f0[1]));
            u.h[1] = __float22bfloat162_rn(make_float2(f1[0], f1[1]));
            u.h[2] = __float22bfloat162_rn(make_float2(f2[0], f2[1]));
            u.h[3] = __float22bfloat162_rn(make_float2(f3[0], f3[1]));
            acc = __builtin_amdgcn_mfma_f32_16x16x32_bf16(u.v, bfr[s], acc, 0, 0, 0);
        }

        // ---- softmax col-sum + h reduction (hb aliases sq; sq consumed) ----
        const float wj = col_weight(acc);
        float2 h = reduce_h(bfr, wj, hb, m, q, lane);

        // ---- residual + cast, into the z LDS tile ----
        float2 xc = __bfloat1622float2(rxv[it]);
        const int row = wv * 4 + it;
        *(__hip_bfloat162*)(&zt[row][2 * lane]) =
            __float22bfloat162_rn(make_float2(xc.x + h.x, xc.y + h.y));

        if (it < 3) cur = nxt;
    }

    __syncthreads();

    // ---- fused linear: out[16 nodes][128] = relu(zt @ W^T + b) ----
    bf16x8 zfr[4];
    #pragma unroll
    for (int s = 0; s < 4; ++s)
        zfr[s] = *(const bf16x8*)(&zt[m][s * 32 + q * 8]);

    #pragma unroll
    for (int half = 0; half < 2; ++half) {
        const int ct = wv * 2 + half;            // cout-tile 0..7
        const __hip_bfloat16* wp = wh + (size_t)(ct * 16 + m) * CC + q * 8;
        bf16x8 wfr[4];
        #pragma unroll
        for (int s = 0; s < 4; ++s)
            wfr[s] = *(const bf16x8*)(wp + s * 32);
        const float bv = bias[ct * 16 + m];
        f32x4 acc = {0.f, 0.f, 0.f, 0.f};
        #pragma unroll
        for (int s = 0; s < 4; ++s)
            acc = __builtin_amdgcn_mfma_f32_16x16x32_bf16(zfr[s], wfr[s], acc, 0, 0, 0);
        // C/D layout: col = lane&15 = cout-in-tile, row = q*4+i = node-in-tile
        float* op = out + (size_t)(base + q * 4) * COUT + ct * 16 + m;
        #pragma unroll
        for (int i = 0; i < 4; ++i)
            op[(size_t)i * COUT] = fmaxf(acc[i] + bv, 0.f);
    }
}

extern "C" void kernel_launch(void* const* d_in, const int* in_sizes, int n_in,
                              void* d_out, int out_size, void* d_ws, size_t ws_size,
                              hipStream_t stream) {
    const float* x    = (const float*)d_in[0];
    const int*   edge = (const int*)d_in[1];
    const float* W    = (const float*)d_in[2];
    const float* bias = (const float*)d_in[3];
    float* out = (float*)d_out;
    __hip_bfloat16* xh = (__hip_bfloat16*)d_ws;                              // 8 MB
    unsigned char*  xq = (unsigned char*)d_ws + 8 * 1024 * 1024;             // 4 MB
    __hip_bfloat16* wh = (__hip_bfloat16*)((char*)d_ws + 12 * 1024 * 1024);  // 32 KB

    cast_x<<<XBLK + (COUT * CC) / (256 * 8), 256, 0, stream>>>(x, xh, xq, W, wh);
    attn_fused<<<NODES / 16, 256, 0, stream>>>(xh, xq, edge, wh, bias, out);
}